// Round 1
// 391.841 us; speedup vs baseline: 1.0176x; 1.0176x over previous
//
#include <hip/hip_runtime.h>

// cluster_layer: q[n,k] = (1/(1+||x_n - c_k||^2)) normalized over k  (alpha=1)
// N=1e6, D=64, K=20.
//
// R2: one row/thread, 16 contiguous dwordx4 per row, clusters as wave-uniform
// scalar (SGPR) operands. Landed at 153 us kernel / 1546 GB/s = 19% peak.
// rocprof: VGPR_Count=64 -> compiler sank the 16 x-loads into the consumer
// loop (only ~2-3 outstanding), latency-bound, not BW-bound.
//
// R3: force 16-deep MLP per wave.
//  - all 16 global_load_dwordx4 issued back-to-back, pinned above a
//    sched_barrier(0) so they cannot be sunk -> full xv[16] kept live
//    (~96-110 VGPRs, fits the 128-VGPR cap of launch_bounds(256,4)).
//  - xsq folded into the per-m loop so the first consumer group only waits
//    vmcnt(15), not vmcnt(0): descending waitcnt pipeline.

#define NPTS 1000000
#define DIM  64
#define KCL  20
#define BLOCK 256

__global__ __launch_bounds__(BLOCK, 4) void cluster_q_kernel(
    const float* __restrict__ x,
    const float* __restrict__ c,
    float* __restrict__ out)
{
    __shared__ float sCsq[KCL];

    // per-block csq (tiny: 20 lanes x 64 reads, c is L2-hot after block 0)
    if (threadIdx.x < KCL) {
        float s = 0.f;
        #pragma unroll
        for (int j = 0; j < DIM; ++j) {
            float v = c[threadIdx.x * DIM + j];
            s += v * v;
        }
        sCsq[threadIdx.x] = s;
    }
    __syncthreads();

    const int row = blockIdx.x * BLOCK + threadIdx.x;
    if (row >= NPTS) return;

    // Issue the entire row: 16 contiguous dwordx4, all in flight at once.
    const float4* __restrict__ x4 = (const float4*)x + (size_t)row * (DIM / 4);
    float4 xv[DIM / 4];
    #pragma unroll
    for (int m = 0; m < DIM / 4; ++m) xv[m] = x4[m];
    // Pin: no consumer may be hoisted above, no load may be sunk below.
    // This is what forces 16-deep MLP (and ~64 VGPRs of live xv).
    __builtin_amdgcn_sched_barrier(0);

    // Dot products: c indices are compile-time constants on a uniform pointer
    // -> s_load -> SGPR operand in v_fma (zero extra VALU, no LDS traffic).
    // xsq folded in so consumer m only depends on xv[m] (descending vmcnt).
    float acc[KCL];
    #pragma unroll
    for (int k = 0; k < KCL; ++k) acc[k] = 0.f;
    float xsq = 0.f;

    #pragma unroll
    for (int m = 0; m < DIM / 4; ++m) {
        xsq += xv[m].x * xv[m].x + xv[m].y * xv[m].y
             + xv[m].z * xv[m].z + xv[m].w * xv[m].w;
        #pragma unroll
        for (int k = 0; k < KCL; ++k) {
            acc[k] += xv[m].x * c[k * DIM + 4 * m + 0]
                    + xv[m].y * c[k * DIM + 4 * m + 1]
                    + xv[m].z * c[k * DIM + 4 * m + 2]
                    + xv[m].w * c[k * DIM + 4 * m + 3];
        }
    }

    // epilogue: d2 -> q -> normalize -> 5 aligned float4 stores
    float s = 0.f;
    #pragma unroll
    for (int k = 0; k < KCL; ++k) {
        float d2 = xsq + sCsq[k] - 2.0f * acc[k];
        float qq = __builtin_amdgcn_rcpf(1.0f + d2);   // v_rcp_f32, ~1 ulp
        acc[k] = qq;
        s += qq;
    }
    const float inv = __builtin_amdgcn_rcpf(s);

    float4* o4 = (float4*)(out + (size_t)row * KCL);
    #pragma unroll
    for (int k = 0; k < KCL; k += 4) {
        float4 v;
        v.x = acc[k + 0] * inv;
        v.y = acc[k + 1] * inv;
        v.z = acc[k + 2] * inv;
        v.w = acc[k + 3] * inv;
        o4[k / 4] = v;
    }
}

extern "C" void kernel_launch(void* const* d_in, const int* in_sizes, int n_in,
                              void* d_out, int out_size, void* d_ws, size_t ws_size,
                              hipStream_t stream) {
    const float* x = (const float*)d_in[0];   // (N, D) fp32
    const float* c = (const float*)d_in[1];   // (K, D) fp32
    float* out = (float*)d_out;               // (N, K) fp32

    const int blocks = (NPTS + BLOCK - 1) / BLOCK;   // 3907
    cluster_q_kernel<<<blocks, BLOCK, 0, stream>>>(x, c, out);
}